// Round 19
// baseline (208.790 us; speedup 1.0000x reference)
//
#include <hip/hip_runtime.h>
#include <hip/hip_bf16.h>
#include <stdint.h>

typedef int   intx4  __attribute__((ext_vector_type(4)));   // i8 MFMA operand / i32 acc
typedef float floatx4 __attribute__((ext_vector_type(4)));

#define BM  256
#define BN  256
#define BKB 128        // K-bytes (= i8 elems) per tile

__device__ __forceinline__ void gload_lds16(const void* g, void* l) {
    auto* gp = reinterpret_cast<const __attribute__((address_space(1))) uint32_t*>(
        reinterpret_cast<uintptr_t>(g));
    auto* lp = reinterpret_cast<__attribute__((address_space(3))) uint32_t*>(
        reinterpret_cast<uintptr_t>(l));
    __builtin_amdgcn_global_load_lds(gp, lp, 16, 0, 0);
}

// ==========================================================================
// Fused per-row quantizer — r18 VERBATIM (at BW floor, ~33us).
// blocks [0,M): x rows -> xq; [M, M+N/4): 4 W-rows each -> wq.
// ==========================================================================
__global__ void quant_fused(const float* __restrict__ x, const float* __restrict__ W,
                            const float* __restrict__ lA, const float* __restrict__ lB,
                            int8_t* __restrict__ xq, int8_t* __restrict__ wq,
                            float* __restrict__ sx, float* __restrict__ sw,
                            long Mrows, int N, int K, int r) {
    __shared__ float red[4][4];        // [row][wave]
    const int tid = threadIdx.x;
    const int wv  = tid >> 6;
    const long b = blockIdx.x;

    if (b < Mrows) {
        const long row = b;
        const float* xr = x + (size_t)row * K;
        float4 v[4];
        float am = 0.f;
#pragma unroll
        for (int i = 0; i < 4; ++i) {
            v[i] = ((const float4*)xr)[i * 256 + tid];
            am = fmaxf(am, fmaxf(fmaxf(fabsf(v[i].x), fabsf(v[i].y)),
                                 fmaxf(fabsf(v[i].z), fabsf(v[i].w))));
        }
#pragma unroll
        for (int off = 32; off; off >>= 1) am = fmaxf(am, __shfl_xor(am, off));
        if ((tid & 63) == 0) red[0][wv] = am;
        __syncthreads();
        am = fmaxf(fmaxf(red[0][0], red[0][1]), fmaxf(red[0][2], red[0][3]));
        const float inv = am > 0.f ? 127.0f / am : 0.f;
        if (tid == 0) sx[row] = am > 0.f ? am / 127.0f : 0.f;
        int8_t* dst = xq + (size_t)row * K;
#pragma unroll
        for (int i = 0; i < 4; ++i) {
            int q0 = min(127, max(-127, (int)rintf(v[i].x * inv)));
            int q1 = min(127, max(-127, (int)rintf(v[i].y * inv)));
            int q2 = min(127, max(-127, (int)rintf(v[i].z * inv)));
            int q3 = min(127, max(-127, (int)rintf(v[i].w * inv)));
            int packed = (q0 & 255) | ((q1 & 255) << 8) | ((q2 & 255) << 16) | (q3 << 24);
            *(int*)(dst + ((size_t)(i * 256 + tid)) * 4) = packed;
        }
    } else {
        const long w0 = (b - Mrows) * 4;
        float4 v[4][4];                // [row][chunk]
#pragma unroll
        for (int rr = 0; rr < 4; ++rr) {
            const float* wr = W + (size_t)(w0 + rr) * K;
#pragma unroll
            for (int i = 0; i < 4; ++i)
                v[rr][i] = ((const float4*)wr)[i * 256 + tid];
        }
        for (int j = 0; j < r; ++j) {
            const float* ar = lA + (size_t)j * K;
            float b0 = lB[(w0 + 0) * r + j];
            float b1 = lB[(w0 + 1) * r + j];
            float b2 = lB[(w0 + 2) * r + j];
            float b3 = lB[(w0 + 3) * r + j];
#pragma unroll
            for (int i = 0; i < 4; ++i) {
                float4 a = ((const float4*)ar)[i * 256 + tid];
                v[0][i].x += b0 * a.x; v[0][i].y += b0 * a.y; v[0][i].z += b0 * a.z; v[0][i].w += b0 * a.w;
                v[1][i].x += b1 * a.x; v[1][i].y += b1 * a.y; v[1][i].z += b1 * a.z; v[1][i].w += b1 * a.w;
                v[2][i].x += b2 * a.x; v[2][i].y += b2 * a.y; v[2][i].z += b2 * a.z; v[2][i].w += b2 * a.w;
                v[3][i].x += b3 * a.x; v[3][i].y += b3 * a.y; v[3][i].z += b3 * a.z; v[3][i].w += b3 * a.w;
            }
        }
#pragma unroll
        for (int rr = 0; rr < 4; ++rr) {
            float a = 0.f;
#pragma unroll
            for (int i = 0; i < 4; ++i)
                a = fmaxf(a, fmaxf(fmaxf(fabsf(v[rr][i].x), fabsf(v[rr][i].y)),
                                   fmaxf(fabsf(v[rr][i].z), fabsf(v[rr][i].w))));
#pragma unroll
            for (int off = 32; off; off >>= 1) a = fmaxf(a, __shfl_xor(a, off));
            if ((tid & 63) == 0) red[rr][wv] = a;
        }
        __syncthreads();
#pragma unroll
        for (int rr = 0; rr < 4; ++rr) {
            float a = fmaxf(fmaxf(red[rr][0], red[rr][1]), fmaxf(red[rr][2], red[rr][3]));
            const float inv = a > 0.f ? 127.0f / a : 0.f;
            if (tid == 0) sw[w0 + rr] = a > 0.f ? a / 127.0f : 0.f;
            int8_t* dst = wq + (size_t)(w0 + rr) * K;
#pragma unroll
            for (int i = 0; i < 4; ++i) {
                int q0 = min(127, max(-127, (int)rintf(v[rr][i].x * inv)));
                int q1 = min(127, max(-127, (int)rintf(v[rr][i].y * inv)));
                int q2 = min(127, max(-127, (int)rintf(v[rr][i].z * inv)));
                int q3 = min(127, max(-127, (int)rintf(v[rr][i].w * inv)));
                int packed = (q0 & 255) | ((q1 & 255) << 8) | ((q2 & 255) << 16) | (q3 << 24);
                *(int*)(dst + ((size_t)(i * 256 + tid)) * 4) = packed;
            }
        }
    }
}

// ==========================================================================
// i8 GEMM, 4-WAVE FAT-WAVE decomposition (r19 change):
// 256 threads, 4 waves (2M x 2N), each wave computes 128x128 output —
// operand LDS-read bytes drop 192KB -> 128KB per tile (A shared x2, B x2
// instead of x4/x2 asymmetric), and the barrier domain shrinks to 4 waves.
// acc[8][8] = 256 AGPR + ~130 operand VGPR -> requires 1 wave/SIMD
// (launch_bounds(256,1), 512-reg budget; m08: spill starts at 512).
// In-wave ILP (64 indep MFMAs/cluster, 32 pipelined ds_reads) replaces TLP.
// Sync: full-drain boundary per K-tile (3x post-timing-stable). Staging:
// linear dest, pre-swizzled source granule (slot s of row l holds granule
// s^(l&7)); per-instruction lane pattern identical to r15-r18 (0 conflicts).
// ==========================================================================
__global__ __launch_bounds__(256, 1)
void gemm_i8w(const int8_t* __restrict__ A,   // [M,K] i8, per-row scale sx
              const int8_t* __restrict__ B,   // [N,K] i8, per-row scale sw
              const float* __restrict__ bias,
              const float* __restrict__ sx, const float* __restrict__ sw,
              float* __restrict__ C,          // [M,N] f32
              int M, int N, int K) {
    __shared__ __align__(16) int8_t lds[2][2][BM * BKB];   // 2 x (A 32KB + B 32KB) = 128 KiB

    const int nbn = N / BN;
    const int nwg = gridDim.x;
    int bid = blockIdx.x;
    int swz = bid;
    if ((nwg & 7) == 0) swz = (bid & 7) * (nwg >> 3) + (bid >> 3);   // XCD swizzle
    const int bm = swz / nbn, bn = swz % nbn;

    const int th   = threadIdx.x;
    const int lane = th & 63;
    const int wid  = th >> 6;          // 0..3
    const int wm = wid >> 1;           // 0..1 -> 128-row slice
    const int wn = wid & 1;            // 0..1 -> 128-col slice
    const int lr = lane & 15;
    const int kg = lane >> 4;          // 16B granule group along K

    const int8_t* gA = A + (size_t)(bm * BM) * K;
    const int8_t* gB = B + (size_t)(bn * BN) * K;
    const int NT = K / BKB;            // 32

    intx4 acc[8][8];
#pragma unroll
    for (int m = 0; m < 8; ++m)
#pragma unroll
        for (int n = 0; n < 8; ++n)
            acc[m][n] = (intx4){0, 0, 0, 0};

    // staging: 256 thr x 16B = 4KB/round = 32 rows; 8 rounds per operand.
    // row l = g*32 + (th>>3); slot = th&7; source granule = (th&7)^(l&7).
    const int srow8 = th >> 3;                      // 0..31
    const int tgr   = (th & 7) ^ (srow8 & 7);       // pre-swizzled src granule

    auto stage = [&](int dbuf, int ab, const int8_t* gbase, int k0) {
#pragma unroll
        for (int g = 0; g < 8; ++g) {
            int l = g * 32 + srow8;                 // row 0..255
            gload_lds16(gbase + (size_t)l * K + k0 + tgr * 16,
                        &lds[dbuf][ab][(size_t)g * 4096 + (size_t)th * 16]);
        }
    };

    auto ldA = [&](const int8_t* base, int mp, int kk) -> intx4 {
        int l = wm * 128 + mp * 16 + lr;
        int c = ((kk << 2) | kg) ^ (lr & 7);
        return *(const intx4*)(base + l * BKB + c * 16);
    };
    auto ldB = [&](const int8_t* base, int np, int kk) -> intx4 {
        int l = wn * 128 + np * 16 + lr;
        int c = ((kk << 2) | kg) ^ (lr & 7);
        return *(const intx4*)(base + l * BKB + c * 16);
    };

    // ---- prologue: stage tile 0, publish (full drain) ----
    stage(0, 0, gA, 0);
    stage(0, 1, gB, 0);
    asm volatile("s_waitcnt vmcnt(0)" ::: "memory");
    asm volatile("s_barrier" ::: "memory");

    for (int t = 0; t < NT; ++t) {
        const int8_t* Ab = &lds[t & 1][0][0];
        const int8_t* Bb = &lds[t & 1][1][0];
        const int nb = (t + 1) & 1;

        if (t + 1 < NT) {
            const int k1 = (t + 1) * BKB;
            stage(nb, 0, gA, k1);
            stage(nb, 1, gB, k1);
        }

        // read all 32 fragments; compiler pipelines lgkmcnt into the MFMAs
        intx4 af[8][2], bf[8][2];
#pragma unroll
        for (int mp = 0; mp < 8; ++mp)
#pragma unroll
            for (int kk = 0; kk < 2; ++kk)
                af[mp][kk] = ldA(Ab, mp, kk);
#pragma unroll
        for (int np = 0; np < 8; ++np)
#pragma unroll
            for (int kk = 0; kk < 2; ++kk)
                bf[np][kk] = ldB(Bb, np, kk);

        // 128 MFMAs, all independent per kk (64-way ILP)
        __builtin_amdgcn_s_setprio(1);
#pragma unroll
        for (int mp = 0; mp < 8; ++mp)
#pragma unroll
            for (int np = 0; np < 8; ++np)
#pragma unroll
                for (int kk = 0; kk < 2; ++kk)
                    acc[mp][np] = __builtin_amdgcn_mfma_i32_16x16x64_i8(
                        af[mp][kk], bf[np][kk], acc[mp][np], 0, 0, 0);
        __builtin_amdgcn_s_setprio(0);

        // boundary: FULL drain — nothing in flight crosses the barrier
        asm volatile("s_waitcnt vmcnt(0)" ::: "memory");
        asm volatile("s_barrier" ::: "memory");
    }

    // ---- epilogue: C/D layout col = lane&15, row = (lane>>4)*4 + q ----
    const int crow = bm * BM + wm * 128;
    const int ccol = bn * BN + wn * 128;
#pragma unroll
    for (int n = 0; n < 8; ++n) {
        int col = ccol + n * 16 + lr;
        float bv  = bias[col];
        float swc = sw[col];
#pragma unroll
        for (int m = 0; m < 8; ++m) {
            int row0 = crow + m * 16 + kg * 4;
            float4 s4 = *(const float4*)&sx[row0];     // row0 % 4 == 0
            C[(size_t)(row0 + 0) * N + col] = (float)acc[m][n][0] * (s4.x * swc) + bv;
            C[(size_t)(row0 + 1) * N + col] = (float)acc[m][n][1] * (s4.y * swc) + bv;
            C[(size_t)(row0 + 2) * N + col] = (float)acc[m][n][2] * (s4.z * swc) + bv;
            C[(size_t)(row0 + 3) * N + col] = (float)acc[m][n][3] * (s4.w * swc) + bv;
        }
    }
}

// ---------- fallback (f32, slow but correct) ----------
__global__ void xa_kernel(const float* __restrict__ x, const float* __restrict__ lA,
                          float* __restrict__ xa, long M, int K, int r) {
    long idx = (long)blockIdx.x * blockDim.x + threadIdx.x;
    long total = M * r;
    if (idx >= total) return;
    long m = idx / r; int j = (int)(idx % r);
    const float* xr = x + m * (long)K;
    const float* ar = lA + (size_t)j * K;
    float s = 0.f;
    for (int k = 0; k < K; k += 4) {
        float4 xv = *(const float4*)&xr[k];
        float4 av = *(const float4*)&ar[k];
        s += xv.x * av.x + xv.y * av.y + xv.z * av.z + xv.w * av.w;
    }
    xa[idx] = s;
}

__global__ void naive_out(const float* __restrict__ x, const float* __restrict__ W,
                          const float* __restrict__ bias, const float* __restrict__ xa,
                          const float* __restrict__ lB, float* __restrict__ out,
                          long M, int N, int K, int r) {
    long idx = (long)blockIdx.x * blockDim.x + threadIdx.x;
    long total = M * (long)N;
    if (idx >= total) return;
    long m = idx / N; int n = (int)(idx % N);
    const float* xr = x + m * (long)K;
    const float* wr = W + (size_t)n * K;
    float s = bias[n];
    for (int k = 0; k < K; k += 4) {
        float4 xv = *(const float4*)&xr[k];
        float4 wv = *(const float4*)&wr[k];
        s += xv.x * wv.x + xv.y * wv.y + xv.z * wv.z + xv.w * wv.w;
    }
    const float* xar = xa + m * r;
    const float* br  = lB + (size_t)n * r;
    for (int j = 0; j < r; ++j) s += xar[j] * br[j];
    out[idx] = s;
}

extern "C" void kernel_launch(void* const* d_in, const int* in_sizes, int n_in,
                              void* d_out, int out_size, void* d_ws, size_t ws_size,
                              hipStream_t stream) {
    const float* x    = (const float*)d_in[0];
    const float* W    = (const float*)d_in[1];
    const float* bias = (const float*)d_in[2];
    const float* lA   = (const float*)d_in[3];
    const float* lB   = (const float*)d_in[4];
    float* out = (float*)d_out;

    const int  N  = in_sizes[2];                  // d_out = 4096
    const int  Kd = in_sizes[1] / N;              // d_in  = 4096
    const int  r  = in_sizes[4] / N;              // 16
    const long M  = (long)in_sizes[0] / Kd;       // B*S   = 8192

    size_t xq_bytes = (size_t)M * Kd;             // i8
    size_t wq_bytes = (size_t)N * Kd;             // i8
    size_t sx_bytes = (size_t)M * sizeof(float);
    size_t sw_bytes = (size_t)N * sizeof(float);

    if (ws_size >= xq_bytes + wq_bytes + sx_bytes + sw_bytes &&
        (M % BM) == 0 && (N % BN) == 0 && (N % 4) == 0 &&
        Kd == 4096 && (Kd / BKB) >= 2) {
        int8_t* xq = (int8_t*)d_ws;
        int8_t* wq = (int8_t*)d_ws + xq_bytes;
        float*  sx = (float*)((char*)d_ws + xq_bytes + wq_bytes);
        float*  sw = sx + M;

        quant_fused<<<(int)(M + N / 4), 256, 0, stream>>>(x, W, lA, lB, xq, wq, sx, sw,
                                                          M, N, Kd, r);

        int grid = (int)(M / BM) * (N / BN);
        gemm_i8w<<<grid, 256, 0, stream>>>(xq, wq, bias, sx, sw, out, (int)M, N, Kd);
    } else {
        // f32 fallback: xa = x @ lA^T  (M x r), then naive out
        float* xa = (float*)d_ws;   // needs M*r*4 bytes = 512 KB
        long total_xa = M * (long)r;
        int blk_xa = (int)((total_xa + 255) / 256);
        xa_kernel<<<blk_xa, 256, 0, stream>>>(x, lA, xa, M, Kd, r);
        long total_o = M * (long)N;
        int blk_o = (int)((total_o + 255) / 256);
        naive_out<<<blk_o, 256, 0, stream>>>(x, W, bias, xa, lB, out, M, N, Kd, r);
    }
}

// Round 20
// 195.023 us; speedup vs baseline: 1.0706x; 1.0706x over previous
//
#include <hip/hip_runtime.h>
#include <hip/hip_bf16.h>
#include <stdint.h>

typedef int   intx4  __attribute__((ext_vector_type(4)));   // i8 MFMA operand / i32 acc
typedef float floatx4 __attribute__((ext_vector_type(4)));

#define BM  256
#define BN  256
#define BKB 128        // K-bytes (= i8 elems) per tile

__device__ __forceinline__ void gload_lds16(const void* g, void* l) {
    auto* gp = reinterpret_cast<const __attribute__((address_space(1))) uint32_t*>(
        reinterpret_cast<uintptr_t>(g));
    auto* lp = reinterpret_cast<__attribute__((address_space(3))) uint32_t*>(
        reinterpret_cast<uintptr_t>(l));
    __builtin_amdgcn_global_load_lds(gp, lp, 16, 0, 0);
}

// ==========================================================================
// Fused per-row quantizer — r18 VERBATIM (at BW floor, ~33us).
// blocks [0,M): x rows -> xq; [M, M+N/4): 4 W-rows each -> wq.
// ==========================================================================
__global__ void quant_fused(const float* __restrict__ x, const float* __restrict__ W,
                            const float* __restrict__ lA, const float* __restrict__ lB,
                            int8_t* __restrict__ xq, int8_t* __restrict__ wq,
                            float* __restrict__ sx, float* __restrict__ sw,
                            long Mrows, int N, int K, int r) {
    __shared__ float red[4][4];        // [row][wave]
    const int tid = threadIdx.x;
    const int wv  = tid >> 6;
    const long b = blockIdx.x;

    if (b < Mrows) {
        const long row = b;
        const float* xr = x + (size_t)row * K;
        float4 v[4];
        float am = 0.f;
#pragma unroll
        for (int i = 0; i < 4; ++i) {
            v[i] = ((const float4*)xr)[i * 256 + tid];
            am = fmaxf(am, fmaxf(fmaxf(fabsf(v[i].x), fabsf(v[i].y)),
                                 fmaxf(fabsf(v[i].z), fabsf(v[i].w))));
        }
#pragma unroll
        for (int off = 32; off; off >>= 1) am = fmaxf(am, __shfl_xor(am, off));
        if ((tid & 63) == 0) red[0][wv] = am;
        __syncthreads();
        am = fmaxf(fmaxf(red[0][0], red[0][1]), fmaxf(red[0][2], red[0][3]));
        const float inv = am > 0.f ? 127.0f / am : 0.f;
        if (tid == 0) sx[row] = am > 0.f ? am / 127.0f : 0.f;
        int8_t* dst = xq + (size_t)row * K;
#pragma unroll
        for (int i = 0; i < 4; ++i) {
            int q0 = min(127, max(-127, (int)rintf(v[i].x * inv)));
            int q1 = min(127, max(-127, (int)rintf(v[i].y * inv)));
            int q2 = min(127, max(-127, (int)rintf(v[i].z * inv)));
            int q3 = min(127, max(-127, (int)rintf(v[i].w * inv)));
            int packed = (q0 & 255) | ((q1 & 255) << 8) | ((q2 & 255) << 16) | (q3 << 24);
            *(int*)(dst + ((size_t)(i * 256 + tid)) * 4) = packed;
        }
    } else {
        const long w0 = (b - Mrows) * 4;
        float4 v[4][4];                // [row][chunk]
#pragma unroll
        for (int rr = 0; rr < 4; ++rr) {
            const float* wr = W + (size_t)(w0 + rr) * K;
#pragma unroll
            for (int i = 0; i < 4; ++i)
                v[rr][i] = ((const float4*)wr)[i * 256 + tid];
        }
        for (int j = 0; j < r; ++j) {
            const float* ar = lA + (size_t)j * K;
            float b0 = lB[(w0 + 0) * r + j];
            float b1 = lB[(w0 + 1) * r + j];
            float b2 = lB[(w0 + 2) * r + j];
            float b3 = lB[(w0 + 3) * r + j];
#pragma unroll
            for (int i = 0; i < 4; ++i) {
                float4 a = ((const float4*)ar)[i * 256 + tid];
                v[0][i].x += b0 * a.x; v[0][i].y += b0 * a.y; v[0][i].z += b0 * a.z; v[0][i].w += b0 * a.w;
                v[1][i].x += b1 * a.x; v[1][i].y += b1 * a.y; v[1][i].z += b1 * a.z; v[1][i].w += b1 * a.w;
                v[2][i].x += b2 * a.x; v[2][i].y += b2 * a.y; v[2][i].z += b2 * a.z; v[2][i].w += b2 * a.w;
                v[3][i].x += b3 * a.x; v[3][i].y += b3 * a.y; v[3][i].z += b3 * a.z; v[3][i].w += b3 * a.w;
            }
        }
#pragma unroll
        for (int rr = 0; rr < 4; ++rr) {
            float a = 0.f;
#pragma unroll
            for (int i = 0; i < 4; ++i)
                a = fmaxf(a, fmaxf(fmaxf(fabsf(v[rr][i].x), fabsf(v[rr][i].y)),
                                   fmaxf(fabsf(v[rr][i].z), fabsf(v[rr][i].w))));
#pragma unroll
            for (int off = 32; off; off >>= 1) a = fmaxf(a, __shfl_xor(a, off));
            if ((tid & 63) == 0) red[rr][wv] = a;
        }
        __syncthreads();
#pragma unroll
        for (int rr = 0; rr < 4; ++rr) {
            float a = fmaxf(fmaxf(red[rr][0], red[rr][1]), fmaxf(red[rr][2], red[rr][3]));
            const float inv = a > 0.f ? 127.0f / a : 0.f;
            if (tid == 0) sw[w0 + rr] = a > 0.f ? a / 127.0f : 0.f;
            int8_t* dst = wq + (size_t)(w0 + rr) * K;
#pragma unroll
            for (int i = 0; i < 4; ++i) {
                int q0 = min(127, max(-127, (int)rintf(v[rr][i].x * inv)));
                int q1 = min(127, max(-127, (int)rintf(v[rr][i].y * inv)));
                int q2 = min(127, max(-127, (int)rintf(v[rr][i].z * inv)));
                int q3 = min(127, max(-127, (int)rintf(v[rr][i].w * inv)));
                int packed = (q0 & 255) | ((q1 & 255) << 8) | ((q2 & 255) << 16) | (q3 << 24);
                *(int*)(dst + ((size_t)(i * 256 + tid)) * 4) = packed;
            }
        }
    }
}

// ==========================================================================
// i8 GEMM — r15/r17/r18 VERBATIM (best measured: 157-163us, post-timing-
// stable three times). Full-drain sync: one vmcnt(0)+barrier boundary per
// K-tile, zero in-flight DMA across any barrier. B in LDS (B-from-global
// regressed twice: r11, r16). 8 waves 2Mx4N (decomposition-optimal 192KB
// LDS reads/tile). Swizzle: LDS slot s of row l holds source granule
// s^(l&7) (0 conflicts measured r15-r18).
// ==========================================================================
__global__ __launch_bounds__(512, 2)
void gemm_i8d(const int8_t* __restrict__ A,   // [M,K] i8, per-row scale sx
              const int8_t* __restrict__ B,   // [N,K] i8, per-row scale sw
              const float* __restrict__ bias,
              const float* __restrict__ sx, const float* __restrict__ sw,
              float* __restrict__ C,          // [M,N] f32
              int M, int N, int K) {
    __shared__ __align__(16) int8_t lds[2][2][BM * BKB];   // 128 KiB

    const int nbn = N / BN;
    const int nwg = gridDim.x;
    int bid = blockIdx.x;
    int swz = bid;
    if ((nwg & 7) == 0) swz = (bid & 7) * (nwg >> 3) + (bid >> 3);   // XCD swizzle
    const int bm = swz / nbn, bn = swz % nbn;

    const int th   = threadIdx.x;
    const int lane = th & 63;
    const int wid  = th >> 6;
    const int wm = wid >> 2;           // 0..1 -> 128-row slice
    const int wn = wid & 3;            // 0..3 -> 64-col slice
    const int lr = lane & 15;
    const int kg = lane >> 4;          // 16B granule group along K

    const int8_t* gA = A + (size_t)(bm * BM) * K;
    const int8_t* gB = B + (size_t)(bn * BN) * K;
    const int NT = K / BKB;            // 32

    intx4 acc[8][4];
#pragma unroll
    for (int m = 0; m < 8; ++m)
#pragma unroll
        for (int n = 0; n < 4; ++n)
            acc[m][n] = (intx4){0, 0, 0, 0};

    const int trow = th >> 3;                       // 0..63 rows per G-load
    const int tgr  = (th & 7) ^ (trow & 7);         // pre-swizzled src granule

    auto stageA = [&](int dbuf, int mh, int k0) {
#pragma unroll
        for (int g = 0; g < 2; ++g) {
            int p = g * 128 + mh * 64 + trow;       // phys A row
            gload_lds16(gA + (size_t)p * K + k0 + tgr * 16,
                        &lds[dbuf][0][(mh * 128 + g * 64) * BKB + th * 16]);
        }
    };
    auto stageB = [&](int dbuf, int nh, int k0) {
#pragma unroll
        for (int g = 0; g < 2; ++g) {
            int rest = g * 64 + trow;               // 0..127
            int p = (rest >> 5) * 64 + nh * 32 + (rest & 31);   // phys B row
            gload_lds16(gB + (size_t)p * K + k0 + tgr * 16,
                        &lds[dbuf][1][(nh * 128 + g * 64) * BKB + th * 16]);
        }
    };

    auto ldA = [&](const int8_t* base, int mh, int mp, int kk) -> intx4 {
        int l = mh * 128 + wm * 64 + mp * 16 + lr;
        int c = ((kk << 2) | kg) ^ (lr & 7);
        return *(const intx4*)(base + l * BKB + c * 16);
    };
    auto ldB = [&](const int8_t* base, int nh, int np, int kk) -> intx4 {
        int l = nh * 128 + wn * 32 + np * 16 + lr;
        int c = ((kk << 2) | kg) ^ (lr & 7);
        return *(const intx4*)(base + l * BKB + c * 16);
    };

    // ---- prologue: stage tile 0, publish (full drain) ----
    stageA(0, 0, 0); stageB(0, 0, 0); stageB(0, 1, 0); stageA(0, 1, 0);
    asm volatile("s_waitcnt vmcnt(0)" ::: "memory");
    asm volatile("s_barrier" ::: "memory");

    for (int t = 0; t < NT; ++t) {
        const int8_t* Ab = &lds[t & 1][0][0];
        const int8_t* Bb = &lds[t & 1][1][0];
        const int nb = (t + 1) & 1;

        if (t + 1 < NT) {
            const int k1 = (t + 1) * BKB;
            stageA(nb, 0, k1);
            stageB(nb, 0, k1);
            stageB(nb, 1, k1);
            stageA(nb, 1, k1);
        }

        intx4 af[4][2], af2[4][2], b0[2][2], b1[2][2];
#pragma unroll
        for (int mp = 0; mp < 4; ++mp)
#pragma unroll
            for (int kk = 0; kk < 2; ++kk)
                af[mp][kk] = ldA(Ab, 0, mp, kk);
#pragma unroll
        for (int np = 0; np < 2; ++np)
#pragma unroll
            for (int kk = 0; kk < 2; ++kk)
                b0[np][kk] = ldB(Bb, 0, np, kk);
#pragma unroll
        for (int np = 0; np < 2; ++np)
#pragma unroll
            for (int kk = 0; kk < 2; ++kk)
                b1[np][kk] = ldB(Bb, 1, np, kk);
#pragma unroll
        for (int mp = 0; mp < 4; ++mp)
#pragma unroll
            for (int kk = 0; kk < 2; ++kk)
                af2[mp][kk] = ldA(Ab, 1, mp, kk);

        __builtin_amdgcn_s_setprio(1);
#pragma unroll
        for (int mp = 0; mp < 4; ++mp)
#pragma unroll
            for (int np = 0; np < 2; ++np)
#pragma unroll
                for (int kk = 0; kk < 2; ++kk)
                    acc[mp][np] = __builtin_amdgcn_mfma_i32_16x16x64_i8(
                        af[mp][kk], b0[np][kk], acc[mp][np], 0, 0, 0);
#pragma unroll
        for (int mp = 0; mp < 4; ++mp)
#pragma unroll
            for (int np = 0; np < 2; ++np)
#pragma unroll
                for (int kk = 0; kk < 2; ++kk)
                    acc[mp][2 + np] = __builtin_amdgcn_mfma_i32_16x16x64_i8(
                        af[mp][kk], b1[np][kk], acc[mp][2 + np], 0, 0, 0);
#pragma unroll
        for (int mp = 0; mp < 4; ++mp)
#pragma unroll
            for (int np = 0; np < 2; ++np)
#pragma unroll
                for (int kk = 0; kk < 2; ++kk)
                    acc[4 + mp][np] = __builtin_amdgcn_mfma_i32_16x16x64_i8(
                        af2[mp][kk], b0[np][kk], acc[4 + mp][np], 0, 0, 0);
#pragma unroll
        for (int mp = 0; mp < 4; ++mp)
#pragma unroll
            for (int np = 0; np < 2; ++np)
#pragma unroll
                for (int kk = 0; kk < 2; ++kk)
                    acc[4 + mp][2 + np] = __builtin_amdgcn_mfma_i32_16x16x64_i8(
                        af2[mp][kk], b1[np][kk], acc[4 + mp][2 + np], 0, 0, 0);
        __builtin_amdgcn_s_setprio(0);

        asm volatile("s_waitcnt vmcnt(0)" ::: "memory");
        asm volatile("s_barrier" ::: "memory");
    }

    // ---- epilogue: C/D layout col = lane&15, row = (lane>>4)*4 + q ----
    const int crow = bm * BM + wm * 128;
    const int ccol = bn * BN + wn * 64;
#pragma unroll
    for (int n = 0; n < 4; ++n) {
        int col = ccol + n * 16 + lr;
        float bv  = bias[col];
        float swc = sw[col];
#pragma unroll
        for (int m = 0; m < 8; ++m) {
            int row0 = crow + m * 16 + kg * 4;
            float4 s4 = *(const float4*)&sx[row0];     // row0 % 4 == 0
            C[(size_t)(row0 + 0) * N + col] = (float)acc[m][n][0] * (s4.x * swc) + bv;
            C[(size_t)(row0 + 1) * N + col] = (float)acc[m][n][1] * (s4.y * swc) + bv;
            C[(size_t)(row0 + 2) * N + col] = (float)acc[m][n][2] * (s4.z * swc) + bv;
            C[(size_t)(row0 + 3) * N + col] = (float)acc[m][n][3] * (s4.w * swc) + bv;
        }
    }
}

// ---------- fallback (f32, slow but correct) ----------
__global__ void xa_kernel(const float* __restrict__ x, const float* __restrict__ lA,
                          float* __restrict__ xa, long M, int K, int r) {
    long idx = (long)blockIdx.x * blockDim.x + threadIdx.x;
    long total = M * r;
    if (idx >= total) return;
    long m = idx / r; int j = (int)(idx % r);
    const float* xr = x + m * (long)K;
    const float* ar = lA + (size_t)j * K;
    float s = 0.f;
    for (int k = 0; k < K; k += 4) {
        float4 xv = *(const float4*)&xr[k];
        float4 av = *(const float4*)&ar[k];
        s += xv.x * av.x + xv.y * av.y + xv.z * av.z + xv.w * av.w;
    }
    xa[idx] = s;
}

__global__ void naive_out(const float* __restrict__ x, const float* __restrict__ W,
                          const float* __restrict__ bias, const float* __restrict__ xa,
                          const float* __restrict__ lB, float* __restrict__ out,
                          long M, int N, int K, int r) {
    long idx = (long)blockIdx.x * blockDim.x + threadIdx.x;
    long total = M * (long)N;
    if (idx >= total) return;
    long m = idx / N; int n = (int)(idx % N);
    const float* xr = x + m * (long)K;
    const float* wr = W + (size_t)n * K;
    float s = bias[n];
    for (int k = 0; k < K; k += 4) {
        float4 xv = *(const float4*)&xr[k];
        float4 wv = *(const float4*)&wr[k];
        s += xv.x * wv.x + xv.y * wv.y + xv.z * wv.z + xv.w * wv.w;
    }
    const float* xar = xa + m * r;
    const float* br  = lB + (size_t)n * r;
    for (int j = 0; j < r; ++j) s += xar[j] * br[j];
    out[idx] = s;
}

extern "C" void kernel_launch(void* const* d_in, const int* in_sizes, int n_in,
                              void* d_out, int out_size, void* d_ws, size_t ws_size,
                              hipStream_t stream) {
    const float* x    = (const float*)d_in[0];
    const float* W    = (const float*)d_in[1];
    const float* bias = (const float*)d_in[2];
    const float* lA   = (const float*)d_in[3];
    const float* lB   = (const float*)d_in[4];
    float* out = (float*)d_out;

    const int  N  = in_sizes[2];                  // d_out = 4096
    const int  Kd = in_sizes[1] / N;              // d_in  = 4096
    const int  r  = in_sizes[4] / N;              // 16
    const long M  = (long)in_sizes[0] / Kd;       // B*S   = 8192

    size_t xq_bytes = (size_t)M * Kd;             // i8
    size_t wq_bytes = (size_t)N * Kd;             // i8
    size_t sx_bytes = (size_t)M * sizeof(float);
    size_t sw_bytes = (size_t)N * sizeof(float);

    if (ws_size >= xq_bytes + wq_bytes + sx_bytes + sw_bytes &&
        (M % BM) == 0 && (N % BN) == 0 && (N % 4) == 0 &&
        Kd == 4096 && (Kd / BKB) >= 2) {
        int8_t* xq = (int8_t*)d_ws;
        int8_t* wq = (int8_t*)d_ws + xq_bytes;
        float*  sx = (float*)((char*)d_ws + xq_bytes + wq_bytes);
        float*  sw = sx + M;

        quant_fused<<<(int)(M + N / 4), 256, 0, stream>>>(x, W, lA, lB, xq, wq, sx, sw,
                                                          M, N, Kd, r);

        int grid = (int)(M / BM) * (N / BN);
        gemm_i8d<<<grid, 512, 0, stream>>>(xq, wq, bias, sx, sw, out, (int)M, N, Kd);
    } else {
        // f32 fallback: xa = x @ lA^T  (M x r), then naive out
        float* xa = (float*)d_ws;   // needs M*r*4 bytes = 512 KB
        long total_xa = M * (long)r;
        int blk_xa = (int)((total_xa + 255) / 256);
        xa_kernel<<<blk_xa, 256, 0, stream>>>(x, lA, xa, M, Kd, r);
        long total_o = M * (long)N;
        int blk_o = (int)((total_o + 255) / 256);
        naive_out<<<blk_o, 256, 0, stream>>>(x, W, bias, xa, lB, out, M, N, Kd, r);
    }
}